// Round 1
// baseline (1644.318 us; speedup 1.0000x reference)
//
#include <hip/hip_runtime.h>

// DownSampler: x[16,3,512,512] -> (fold C into N: 48 images, 1 ch each)
//  S1: reflect-pad1 + 4x4 s2 conv (1->20) + relu   -> [48,20,256,256]
//  S2: reflect-pad1 + 4x4 s2 conv (20->20) + relu  -> [48,20,128,128]
//  S3: 3x3 zero-pad1 conv (20->1) + relu           -> [48,128,128] = [16,3,128,128]
//
// Fully fused, one block per 16x16 output tile. 48*64 = 3072 blocks, 320 thr.
// o1/o2 staged in LDS as bf16 (halves LDS -> 2 blocks/CU). Weights read with
// thread-uniform indices -> scalar loads (s_load), costing no VALU/LDS.

#define NC 20

__device__ __forceinline__ unsigned short f2bf(float v) {
    unsigned int b = __float_as_uint(v);
    b += 0x7fffu + ((b >> 16) & 1u);   // RNE
    return (unsigned short)(b >> 16);
}
__device__ __forceinline__ float bf2f(unsigned short u) {
    return __uint_as_float(((unsigned int)u) << 16);
}

__global__ __launch_bounds__(320) void ds_fused(
    const float* __restrict__ x,    // [48][512][512]
    const float* __restrict__ w1,   // [20][1][4][4]  = [20][16]
    const float* __restrict__ w2,   // [20][20][4][4] = [20][20][16]
    const float* __restrict__ w3,   // [1][20][3][3]  = [20][9]
    float* __restrict__ out)        // [48][128][128]
{
    // o1 tile: o1pad indices t in [P0, P0+38) per axis, 20 channels, bf16
    __shared__ unsigned short s_o1[NC][38][38];   // 57,760 B
    // o2 tile: 18x18 (tile+1 halo each side), 20 channels, bf16
    __shared__ unsigned short s_o2[NC][18][18];   // 12,960 B

    const int bid  = blockIdx.x;
    const int img  = bid >> 6;            // bid / 64
    const int tile = bid & 63;
    const int y0   = (tile >> 3) << 4;    // tile row * 16
    const int x0   = (tile & 7) << 4;     // tile col * 16
    const int tid  = threadIdx.x;

    const float* __restrict__ xi = x + (size_t)img * (512 * 512);
    const int P0 = 2 * y0 - 2;            // o1pad row base of the tile
    const int Q0 = 2 * x0 - 2;            // o1pad col base

    // ---------------- Stage A: x -> o1 tile (bf16 in LDS) ----------------
    for (int p = tid; p < 38 * 38; p += 320) {
        const int a = p / 38;
        const int b = p - a * 38;
        const int t = P0 + a;             // o1pad row index
        const int s = Q0 + b;             // o1pad col index
        if (t >= 0 && t < 258 && s >= 0 && s < 258) {
            // reflect o1pad -> o1 coords (pad=1 reflect, 256 wide)
            int m = t - 1; m = (m < 0) ? -m : m; m = (m > 255) ? 510 - m : m;
            int n = s - 1; n = (n < 0) ? -n : n; n = (n > 255) ? 510 - n : n;
            // gather the 4x4 x patch (xpad rows 2m..2m+3 => x rows reflect(2m-1+ki))
            float xv[16];
            #pragma unroll
            for (int ki = 0; ki < 4; ++ki) {
                int u = 2 * m - 1 + ki;
                u = (u < 0) ? -u : u; u = (u > 511) ? 1022 - u : u;
                const float* __restrict__ xrow = xi + u * 512;
                #pragma unroll
                for (int kj = 0; kj < 4; ++kj) {
                    int v = 2 * n - 1 + kj;
                    v = (v < 0) ? -v : v; v = (v > 511) ? 1022 - v : v;
                    xv[ki * 4 + kj] = xrow[v];
                }
            }
            for (int ch = 0; ch < NC; ++ch) {       // w1 index uniform -> s_load
                float acc = 0.f;
                #pragma unroll
                for (int k = 0; k < 16; ++k)
                    acc = fmaf(xv[k], w1[ch * 16 + k], acc);
                s_o1[ch][a][b] = f2bf(fmaxf(acc, 0.f));
            }
        } else {
            for (int ch = 0; ch < NC; ++ch) s_o1[ch][a][b] = 0;
        }
    }
    __syncthreads();

    // ---------------- Stage B: o1 tile -> o2 tile (bf16 in LDS) ----------------
    // One thread per o2 position (18x18=324), all 20 couts in registers so the
    // w2 index stays thread-uniform (scalar loads).
    for (int q = tid; q < 18 * 18; q += 320) {
        const int il = q / 18;
        const int jl = q - il * 18;
        const int i = y0 - 1 + il;        // o2 row (may be -1/128: zero-pad row)
        const int j = x0 - 1 + jl;
        float acc[NC];
        #pragma unroll
        for (int c = 0; c < NC; ++c) acc[c] = 0.f;

        if (i >= 0 && i < 128 && j >= 0 && j < 128) {
            const int a0 = 2 * il;        // o1pad row 2i  -> local a = 2*il + ki
            const int b0 = 2 * jl;
            for (int cin = 0; cin < NC; ++cin) {
                float o1r[16];
                #pragma unroll
                for (int ki = 0; ki < 4; ++ki)
                    #pragma unroll
                    for (int kj = 0; kj < 4; ++kj)
                        o1r[ki * 4 + kj] = bf2f(s_o1[cin][a0 + ki][b0 + kj]);
                const float* __restrict__ w2c = w2 + cin * 16;
                #pragma unroll
                for (int c = 0; c < NC; ++c) {      // uniform index -> s_load
                    #pragma unroll
                    for (int k = 0; k < 16; ++k)
                        acc[c] = fmaf(o1r[k], w2c[c * (NC * 16) + k], acc[c]);
                }
            }
        }
        #pragma unroll
        for (int c = 0; c < NC; ++c)
            s_o2[c][il][jl] = f2bf(fmaxf(acc[c], 0.f));   // zero rows stay zero
    }
    __syncthreads();

    // ---------------- Stage C: o2 tile -> out (3x3, zero pad already in tile) ---
    if (tid < 256) {
        const int oy = tid >> 4;
        const int ox = tid & 15;
        float acc = 0.f;
        for (int c = 0; c < NC; ++c) {              // w3 uniform -> s_load
            #pragma unroll
            for (int di = 0; di < 3; ++di)
                #pragma unroll
                for (int dj = 0; dj < 3; ++dj)
                    acc = fmaf(bf2f(s_o2[c][oy + di][ox + dj]),
                               w3[c * 9 + di * 3 + dj], acc);
        }
        out[(size_t)img * (128 * 128) + (y0 + oy) * 128 + (x0 + ox)] =
            fmaxf(acc, 0.f);
    }
}

extern "C" void kernel_launch(void* const* d_in, const int* in_sizes, int n_in,
                              void* d_out, int out_size, void* d_ws, size_t ws_size,
                              hipStream_t stream) {
    const float* x  = (const float*)d_in[0];
    const float* w1 = (const float*)d_in[1];
    const float* w2 = (const float*)d_in[2];
    const float* w3 = (const float*)d_in[3];
    float* out = (float*)d_out;
    ds_fused<<<dim3(48 * 64), dim3(320), 0, stream>>>(x, w1, w2, w3, out);
}

// Round 2
// 419.831 us; speedup vs baseline: 3.9166x; 3.9166x over previous
//
#include <hip/hip_runtime.h>

// DownSampler fused: x[16,3,512,512] -> out[16,3,128,128] (C folded into N: 48 imgs)
//  S1: reflect-pad1 + 4x4/s2 conv (1->20) + relu
//  S2: reflect-pad1 + 4x4/s2 conv (20->20) + relu
//  S3: 3x3 zero-pad1 conv (20->1) + relu
//
// One block per 14x14 output tile (o2 tile 16x16 == 256 threads -> stage B is
// exactly one full round; round-quantization fixed vs round 1). Stage-1
// channels processed in groups of 5 so s_o1 is 11.6 KB; x window staged once
// in LDS as bf16 in reflect-padded coords. Total LDS 31.9 KB -> ~5 blocks/CU.

#define NC 20
#define G  5      // stage-1 channel group
#define TS 14     // output tile
#define OT 16     // o2 tile (TS + 2 halo)
#define AT 34     // o1pad tile (2*OT + 2)
#define XW 70     // xpad window rows
#define XWC 72    // xpad window cols (padded even)

__device__ __forceinline__ unsigned short f2bf(float v) {
    unsigned int b = __float_as_uint(v);
    b += 0x7fffu + ((b >> 16) & 1u);   // RNE
    return (unsigned short)(b >> 16);
}

__global__ __launch_bounds__(256, 4) void ds_fused(
    const float* __restrict__ x,    // [48][512][512]
    const float* __restrict__ w1,   // [20][16]
    const float* __restrict__ w2,   // [20][20][16]
    const float* __restrict__ w3,   // [20][9]
    float* __restrict__ out)        // [48][128][128]
{
    __shared__ __attribute__((aligned(16))) unsigned short s_xp[XW * XWC];   // 10,080 B
    __shared__ __attribute__((aligned(16))) unsigned short s_o1[G][AT * AT]; // 11,560 B
    __shared__ __attribute__((aligned(16))) unsigned short s_o2[NC][OT * OT];// 10,240 B

    const int bid  = blockIdx.x;
    const int img  = bid / 100;
    const int t100 = bid - img * 100;
    const int ty   = t100 / 10;
    const int tx   = t100 - ty * 10;
    const int y0   = ty * TS;
    const int x0   = tx * TS;
    const int tid  = threadIdx.x;

    const float* __restrict__ xi = x + (size_t)img * (512 * 512);

    // xpad-space window anchor (xpad = reflect-pad1 of x, 514x514 virtual).
    // All stage-A reads land in [R0, R0+69] x [C0, C0+69] (verified incl. borders).
    const int R0 = max(0, 4 * y0 - 6);
    const int C0 = max(0, 4 * x0 - 6);

    // ---- stage X: global -> s_xp (bf16), reflect folded into the load ----
    for (int p = tid; p < XW * XWC; p += 256) {
        const int pr = p / XWC;
        const int qc = p - pr * XWC;
        const int P = R0 + pr;          // xpad row
        const int Q = C0 + qc;          // xpad col
        float v = 0.f;
        if (P <= 513 && Q <= 513) {
            int gr = P - 1; gr = (gr < 0) ? -gr : gr; gr = (gr > 511) ? 1022 - gr : gr;
            int gc = Q - 1; gc = (gc < 0) ? -gc : gc; gc = (gc > 511) ? 1022 - gc : gc;
            v = xi[gr * 512 + gc];
        }
        s_xp[p] = f2bf(v);
    }

    float acc[NC];
    #pragma unroll
    for (int c = 0; c < NC; ++c) acc[c] = 0.f;

    const int t0 = 2 * y0 - 2;          // o1pad row base of tile
    const int s0 = 2 * x0 - 2;
    const int il = tid >> 4, jl = tid & 15;       // o2 tile coords (16x16)
    const int oi = y0 - 1 + il, oj = x0 - 1 + jl; // global o2 coords
    const bool bvalid = (oi >= 0 && oi < 128 && oj >= 0 && oj < 128);

    __syncthreads();

    for (int g = 0; g < NC / G; ++g) {
        if (g) __syncthreads();         // prev stage-B reads of s_o1 done

        // ---- stage A: s_xp -> s_o1[g-group] ----
        const float* __restrict__ w1g = w1 + g * G * 16;
        for (int p = tid; p < AT * AT; p += 256) {
            const int a = p / AT;
            const int b = p - a * AT;
            const int t = t0 + a;       // o1pad row
            const int s = s0 + b;       // o1pad col
            if (t >= 0 && t <= 257 && s >= 0 && s <= 257) {
                int m = t - 1; m = (m < 0) ? -m : m; m = (m > 255) ? 510 - m : m;
                int n = s - 1; n = (n < 0) ? -n : n; n = (n > 255) ? 510 - n : n;
                const int pb = 2 * m - R0;   // window row of xpad row 2m
                const int qb = 2 * n - C0;   // window col (even -> 4B aligned)
                float xv[16];
                #pragma unroll
                for (int ki = 0; ki < 4; ++ki) {
                    const unsigned short* row = &s_xp[(pb + ki) * XWC + qb];
                    const unsigned int d0 = *(const unsigned int*)(row);
                    const unsigned int d1 = *(const unsigned int*)(row + 2);
                    xv[ki * 4 + 0] = __uint_as_float(d0 << 16);
                    xv[ki * 4 + 1] = __uint_as_float(d0 & 0xffff0000u);
                    xv[ki * 4 + 2] = __uint_as_float(d1 << 16);
                    xv[ki * 4 + 3] = __uint_as_float(d1 & 0xffff0000u);
                }
                #pragma unroll
                for (int cl = 0; cl < G; ++cl) {     // w1 uniform -> s_load
                    float o = 0.f;
                    #pragma unroll
                    for (int k = 0; k < 16; ++k)
                        o = fmaf(xv[k], w1g[cl * 16 + k], o);
                    s_o1[cl][a * AT + b] = f2bf(fmaxf(o, 0.f));
                }
            }
            // skipped slots are never read by stage B
        }
        __syncthreads();

        // ---- stage B partial: s_o1 -> acc[20] (registers) ----
        if (bvalid) {
            const int a0 = 2 * il, b0 = 2 * jl;      // b0 even -> 4B aligned
            #pragma unroll
            for (int cl = 0; cl < G; ++cl) {
                float o1r[16];
                #pragma unroll
                for (int ki = 0; ki < 4; ++ki) {
                    const unsigned short* row = &s_o1[cl][(a0 + ki) * AT + b0];
                    const unsigned int d0 = *(const unsigned int*)(row);
                    const unsigned int d1 = *(const unsigned int*)(row + 2);
                    o1r[ki * 4 + 0] = __uint_as_float(d0 << 16);
                    o1r[ki * 4 + 1] = __uint_as_float(d0 & 0xffff0000u);
                    o1r[ki * 4 + 2] = __uint_as_float(d1 << 16);
                    o1r[ki * 4 + 3] = __uint_as_float(d1 & 0xffff0000u);
                }
                const float* __restrict__ w2g = w2 + (g * G + cl) * 16;
                #pragma unroll
                for (int c = 0; c < NC; ++c) {       // w2 uniform -> s_load
                    #pragma unroll
                    for (int k = 0; k < 16; ++k)
                        acc[c] = fmaf(o1r[k], w2g[c * (NC * 16) + k], acc[c]);
                }
            }
        }
    }

    // ---- write s_o2 (zeros at zero-pad / out-of-image positions) ----
    #pragma unroll
    for (int c = 0; c < NC; ++c)
        s_o2[c][il * OT + jl] = bvalid ? f2bf(fmaxf(acc[c], 0.f)) : (unsigned short)0;
    __syncthreads();

    // ---- stage C: 3x3 conv over s_o2 -> out ----
    if (tid < TS * TS) {
        const int oy = tid / TS;
        const int ox = tid - oy * TS;
        const int e  = ox & ~1;          // aligned pair base (covers ox..ox+2)
        const int par = ox & 1;
        float accc = 0.f;
        for (int c = 0; c < NC; ++c) {   // w3 uniform -> s_load
            #pragma unroll
            for (int di = 0; di < 3; ++di) {
                const unsigned short* row = &s_o2[c][(oy + di) * OT + e];
                const unsigned int d0 = *(const unsigned int*)(row);
                const unsigned int d1 = *(const unsigned int*)(row + 2);
                const float v0 = __uint_as_float(d0 << 16);
                const float v1 = __uint_as_float(d0 & 0xffff0000u);
                const float v2 = __uint_as_float(d1 << 16);
                const float v3 = __uint_as_float(d1 & 0xffff0000u);
                const float u0 = par ? v1 : v0;
                const float u1 = par ? v2 : v1;
                const float u2 = par ? v3 : v2;
                const float* w3r = w3 + c * 9 + di * 3;
                accc = fmaf(u0, w3r[0], accc);
                accc = fmaf(u1, w3r[1], accc);
                accc = fmaf(u2, w3r[2], accc);
            }
        }
        const int gy = y0 + oy, gx = x0 + ox;
        if (gy < 128 && gx < 128)
            out[(size_t)img * (128 * 128) + gy * 128 + gx] = fmaxf(accc, 0.f);
    }
}

extern "C" void kernel_launch(void* const* d_in, const int* in_sizes, int n_in,
                              void* d_out, int out_size, void* d_ws, size_t ws_size,
                              hipStream_t stream) {
    const float* x  = (const float*)d_in[0];
    const float* w1 = (const float*)d_in[1];
    const float* w2 = (const float*)d_in[2];
    const float* w3 = (const float*)d_in[3];
    float* out = (float*)d_out;
    ds_fused<<<dim3(48 * 100), dim3(256), 0, stream>>>(x, w1, w2, w3, out);
}

// Round 4
// 333.574 us; speedup vs baseline: 4.9294x; 1.2586x over previous
//
#include <hip/hip_runtime.h>

// DownSampler fused: x[16,3,512,512] -> out[16,3,128,128] (C folded into N: 48 imgs)
//  S1: reflect-pad1 + 4x4/s2 conv (1->20) + relu
//  S2: reflect-pad1 + 4x4/s2 conv (20->20) + relu
//  S3: 3x3 zero-pad1 conv (20->1) + relu
//
// Round 4 = round 3 (f16 staging + v_dot2_f32_f16 everywhere, packed weights
// in d_ws) with the stage-C edge guard RESTORED (round 3's only bug: tiles
// cover 140>128 px, unguarded stores corrupted neighboring images).

#define NC 20
#define G  5      // stage-1 channel group
#define TS 14     // output tile
#define OT 16     // o2 tile (TS + 2 halo)
#define AT 34     // o1pad tile
#define XW 70     // xpad window rows
#define XWC 72    // xpad window cols (even)

// d_ws layout (u32 packed f16 pairs):
//   [0,160)      w1p[ch][kp]              ch<20, kp<8   (k = 2kp,2kp+1)
//   [160,3360)   w2p[cin][cout][kp]       20*20*8
//   [3360,3540)  w3p[c][di][which]        which: 0=(w0,w1) 1=(w2,0) 2=(0,w2)
#define W2_OFF 160
#define W3_OFF 3360
#define WP_N   3540

typedef _Float16 h2 __attribute__((ext_vector_type(2)));

__device__ __forceinline__ float dot2(unsigned int a, unsigned int b, float c) {
    return __builtin_amdgcn_fdot2(__builtin_bit_cast(h2, a),
                                  __builtin_bit_cast(h2, b), c, false);
}
__device__ __forceinline__ unsigned int packh(float a, float b) {
    _Float16 ha = (_Float16)a, hb = (_Float16)b;
    return (unsigned int)__builtin_bit_cast(unsigned short, ha) |
           ((unsigned int)__builtin_bit_cast(unsigned short, hb) << 16);
}
__device__ __forceinline__ unsigned short f2h(float a) {
    _Float16 h = (_Float16)a;
    return __builtin_bit_cast(unsigned short, h);
}

__global__ __launch_bounds__(256) void pack_weights(
    const float* __restrict__ w1, const float* __restrict__ w2,
    const float* __restrict__ w3, unsigned int* __restrict__ wp)
{
    const int i = blockIdx.x * 256 + threadIdx.x;
    if (i >= WP_N) return;
    float a, b;
    if (i < W2_OFF) {                       // w1: ch = i>>3, kp = i&7
        const int ch = i >> 3, kp = i & 7;
        a = w1[ch * 16 + 2 * kp];
        b = w1[ch * 16 + 2 * kp + 1];
    } else if (i < W3_OFF) {                // w2p[cin][cout][kp]
        const int t = i - W2_OFF;
        const int cin = t / 160;
        const int r = t - cin * 160;
        const int cout = r >> 3, kp = r & 7;
        a = w2[(cout * NC + cin) * 16 + 2 * kp];
        b = w2[(cout * NC + cin) * 16 + 2 * kp + 1];
    } else {                                // w3p[c][di][which]
        const int t = i - W3_OFF;
        const int c = t / 9;
        const int r = t - c * 9;
        const int di = r / 3, wh = r - di * 3;
        const float* row = w3 + c * 9 + di * 3;
        if (wh == 0)      { a = row[0]; b = row[1]; }
        else if (wh == 1) { a = row[2]; b = 0.f;    }
        else              { a = 0.f;    b = row[2]; }
    }
    wp[i] = packh(a, b);
}

__global__ __launch_bounds__(256, 4) void ds_fused(
    const float* __restrict__ x,              // [48][512][512]
    const unsigned int* __restrict__ wp,      // packed weights (d_ws)
    float* __restrict__ out)                  // [48][128][128]
{
    __shared__ __attribute__((aligned(16))) unsigned short s_xp[XW * XWC];   // 10,080 B
    __shared__ __attribute__((aligned(16))) unsigned short s_o1[G][AT * AT]; // 11,560 B
    __shared__ __attribute__((aligned(16))) unsigned short s_o2[NC][OT * OT];// 10,240 B

    const int bid  = blockIdx.x;
    const int img  = bid / 100;
    const int t100 = bid - img * 100;
    const int ty   = t100 / 10;
    const int tx   = t100 - ty * 10;
    const int y0   = ty * TS;
    const int x0   = tx * TS;
    const int tid  = threadIdx.x;

    const float* __restrict__ xi = x + (size_t)img * (512 * 512);
    const unsigned int* __restrict__ w1p = wp;
    const unsigned int* __restrict__ w2p = wp + W2_OFF;
    const unsigned int* __restrict__ w3p = wp + W3_OFF;

    const int R0 = max(0, 4 * y0 - 6);   // xpad window anchor
    const int C0 = max(0, 4 * x0 - 6);

    // ---- stage X: global -> s_xp (f16, packed dword stores) ----
    for (int p2 = tid; p2 < (XW * XWC) / 2; p2 += 256) {
        const int p  = 2 * p2;
        const int pr = p / XWC;
        const int qc = p - pr * XWC;      // even
        const int P  = R0 + pr;
        float v0 = 0.f, v1 = 0.f;
        if (P <= 513) {
            int gr = P - 1; gr = (gr < 0) ? -gr : gr; gr = (gr > 511) ? 1022 - gr : gr;
            const float* __restrict__ xrow = xi + gr * 512;
            int Q0e = C0 + qc;
            if (Q0e <= 513) {
                int gc = Q0e - 1; gc = (gc < 0) ? -gc : gc; gc = (gc > 511) ? 1022 - gc : gc;
                v0 = xrow[gc];
            }
            int Q1 = C0 + qc + 1;
            if (Q1 <= 513) {
                int gc = Q1 - 1; gc = (gc < 0) ? -gc : gc; gc = (gc > 511) ? 1022 - gc : gc;
                v1 = xrow[gc];
            }
        }
        ((unsigned int*)s_xp)[p2] = packh(v0, v1);
    }

    float acc[NC];
    #pragma unroll
    for (int c = 0; c < NC; ++c) acc[c] = 0.f;

    const int t0 = 2 * y0 - 2;            // o1pad row base of tile
    const int s0 = 2 * x0 - 2;
    const int il = tid >> 4, jl = tid & 15;
    const int oi = y0 - 1 + il, oj = x0 - 1 + jl;
    const bool bvalid = (oi >= 0 && oi < 128 && oj >= 0 && oj < 128);

    __syncthreads();

    for (int g = 0; g < NC / G; ++g) {
        if (g) __syncthreads();

        // ---- stage A: s_xp -> s_o1[group g] (f16) ----
        for (int p = tid; p < AT * AT; p += 256) {
            const int a = p / AT;
            const int b = p - a * AT;
            const int t = t0 + a;
            const int s = s0 + b;
            if (t >= 0 && t <= 257 && s >= 0 && s <= 257) {
                int m = t - 1; m = (m < 0) ? -m : m; m = (m > 255) ? 510 - m : m;
                int n = s - 1; n = (n < 0) ? -n : n; n = (n > 255) ? 510 - n : n;
                const int pb = 2 * m - R0;
                const int qb = 2 * n - C0;    // even -> dword aligned
                unsigned int xr[8];
                #pragma unroll
                for (int ki = 0; ki < 4; ++ki) {
                    const unsigned int* row =
                        (const unsigned int*)&s_xp[(pb + ki) * XWC + qb];
                    xr[2 * ki]     = row[0];
                    xr[2 * ki + 1] = row[1];
                }
                #pragma unroll
                for (int cl = 0; cl < G; ++cl) {       // w1p uniform -> s_load
                    const int base = (g * G + cl) * 8;
                    float o = 0.f;
                    #pragma unroll
                    for (int kp = 0; kp < 8; ++kp)
                        o = dot2(xr[kp], w1p[base + kp], o);
                    s_o1[cl][a * AT + b] = f2h(fmaxf(o, 0.f));
                }
            }
        }
        __syncthreads();

        // ---- stage B partial: s_o1 -> acc[20] ----
        if (bvalid) {
            const int a0 = 2 * il, b0 = 2 * jl;        // b0 even -> aligned
            #pragma unroll
            for (int cl = 0; cl < G; ++cl) {
                unsigned int o1r[8];
                #pragma unroll
                for (int ki = 0; ki < 4; ++ki) {
                    const unsigned int* row =
                        (const unsigned int*)&s_o1[cl][(a0 + ki) * AT + b0];
                    o1r[2 * ki]     = row[0];
                    o1r[2 * ki + 1] = row[1];
                }
                const int cing = g * G + cl;
                #pragma unroll
                for (int c = 0; c < NC; ++c) {         // w2p uniform -> s_load
                    const int base = (cing * NC + c) * 8;
                    #pragma unroll
                    for (int kp = 0; kp < 8; ++kp)
                        acc[c] = dot2(o1r[kp], w2p[base + kp], acc[c]);
                }
            }
        }
    }

    // ---- write s_o2 (f16; zeros at pad / out-of-image) ----
    #pragma unroll
    for (int c = 0; c < NC; ++c)
        s_o2[c][il * OT + jl] = bvalid ? f2h(fmaxf(acc[c], 0.f)) : (unsigned short)0;
    __syncthreads();

    // ---- stage C: 3x3 conv over s_o2 -> out ----
    if (tid < TS * TS) {
        const int oy = tid / TS;
        const int ox = tid - oy * TS;
        const int e  = ox & ~1;
        const int par = ox & 1;
        float accc = 0.f;
        for (int c = 0; c < NC; ++c) {
            #pragma unroll
            for (int di = 0; di < 3; ++di) {
                const unsigned int* row =
                    (const unsigned int*)&s_o2[c][(oy + di) * OT + e];
                const unsigned int d0 = row[0];
                const unsigned int d1 = row[1];
                // (v1,v2) from the two dwords for the odd-column case
                const unsigned int m = __builtin_amdgcn_perm(d1, d0, 0x05040302u);
                const unsigned int u0 = par ? m : d0;
                const unsigned int wa = w3p[c * 9 + di * 3 + 0];      // (w0,w1)
                const unsigned int wb = w3p[c * 9 + di * 3 + 1];      // (w2,0)
                const unsigned int wc = w3p[c * 9 + di * 3 + 2];      // (0,w2)
                accc = dot2(u0, wa, accc);
                accc = dot2(d1, par ? wc : wb, accc);
            }
        }
        const int gy = y0 + oy, gx = x0 + ox;
        if (gy < 128 && gx < 128)   // tiles cover 140>128 px: guard edge tiles
            out[(size_t)img * (128 * 128) + gy * 128 + gx] = fmaxf(accc, 0.f);
    }
}

extern "C" void kernel_launch(void* const* d_in, const int* in_sizes, int n_in,
                              void* d_out, int out_size, void* d_ws, size_t ws_size,
                              hipStream_t stream) {
    const float* x  = (const float*)d_in[0];
    const float* w1 = (const float*)d_in[1];
    const float* w2 = (const float*)d_in[2];
    const float* w3 = (const float*)d_in[3];
    unsigned int* wp = (unsigned int*)d_ws;
    float* out = (float*)d_out;
    pack_weights<<<dim3((WP_N + 255) / 256), dim3(256), 0, stream>>>(w1, w2, w3, wp);
    ds_fused<<<dim3(48 * 100), dim3(256), 0, stream>>>(x, wp, out);
}

// Round 6
// 267.318 us; speedup vs baseline: 6.1512x; 1.2479x over previous
//
#include <hip/hip_runtime.h>

// DownSampler fused: x[16,3,512,512] -> out[16,3,128,128] (C folded into N: 48 imgs)
//  S1: reflect-pad1 + 4x4/s2 conv (1->20) + relu
//  S2: reflect-pad1 + 4x4/s2 conv (20->20) + relu
//  S3: 3x3 zero-pad1 conv (20->1) + relu
//
// Round 6 = round 5 with the cvt_pkrtz return-type fixed (__fp16 vector, not
// _Float16 vector). Structure: (a) stage-A x-taps cached in registers across
// the 4 channel-groups (fill once from global, reflect folded in; no s_xp,
// one less barrier); (b) s_o1 row stride 48 shorts => conflict-free stage-B
// reads; (c) LDS 26.6 KB + launch_bounds(256,5) => 5 blocks/CU.

#define NC 20
#define G  5      // stage-1 channel group
#define TS 14     // output tile
#define OT 16     // o2 tile (TS + 2 halo)
#define AT 34     // o1pad tile
#define SO1 48    // s_o1 row stride in shorts (24 dwords, bank-conflict-free)

// d_ws layout (u32 packed f16 pairs):
//   [0,160)      w1p[ch][kp]              ch<20, kp<8
//   [160,3360)   w2p[cin][cout][kp]       20*20*8
//   [3360,3540)  w3p[c][di][which]        which: 0=(w0,w1) 1=(w2,0) 2=(0,w2)
#define W2_OFF 160
#define W3_OFF 3360
#define WP_N   3540

typedef _Float16 h2  __attribute__((ext_vector_type(2)));
typedef __fp16   hq2 __attribute__((ext_vector_type(2)));   // cvt_pkrtz ret type

__device__ __forceinline__ float dot2(unsigned int a, unsigned int b, float c) {
    return __builtin_amdgcn_fdot2(__builtin_bit_cast(h2, a),
                                  __builtin_bit_cast(h2, b), c, false);
}
__device__ __forceinline__ unsigned int packh(float a, float b) {
    _Float16 ha = (_Float16)a, hb = (_Float16)b;
    return (unsigned int)__builtin_bit_cast(unsigned short, ha) |
           ((unsigned int)__builtin_bit_cast(unsigned short, hb) << 16);
}
__device__ __forceinline__ unsigned int pkrtz(float a, float b) {
    hq2 r = __builtin_amdgcn_cvt_pkrtz(a, b);
    return __builtin_bit_cast(unsigned int, r);
}
__device__ __forceinline__ unsigned short f2h(float a) {
    _Float16 h = (_Float16)a;
    return __builtin_bit_cast(unsigned short, h);
}

__global__ __launch_bounds__(256) void pack_weights(
    const float* __restrict__ w1, const float* __restrict__ w2,
    const float* __restrict__ w3, unsigned int* __restrict__ wp)
{
    const int i = blockIdx.x * 256 + threadIdx.x;
    if (i >= WP_N) return;
    float a, b;
    if (i < W2_OFF) {
        const int ch = i >> 3, kp = i & 7;
        a = w1[ch * 16 + 2 * kp];
        b = w1[ch * 16 + 2 * kp + 1];
    } else if (i < W3_OFF) {
        const int t = i - W2_OFF;
        const int cin = t / 160;
        const int r = t - cin * 160;
        const int cout = r >> 3, kp = r & 7;
        a = w2[(cout * NC + cin) * 16 + 2 * kp];
        b = w2[(cout * NC + cin) * 16 + 2 * kp + 1];
    } else {
        const int t = i - W3_OFF;
        const int c = t / 9;
        const int r = t - c * 9;
        const int di = r / 3, wh = r - di * 3;
        const float* row = w3 + c * 9 + di * 3;
        if (wh == 0)      { a = row[0]; b = row[1]; }
        else if (wh == 1) { a = row[2]; b = 0.f;    }
        else              { a = 0.f;    b = row[2]; }
    }
    wp[i] = packh(a, b);
}

__global__ __launch_bounds__(256, 5) void ds_fused(
    const float* __restrict__ x,              // [48][512][512]
    const unsigned int* __restrict__ wp,      // packed weights (d_ws)
    float* __restrict__ out)                  // [48][128][128]
{
    __shared__ __attribute__((aligned(16))) unsigned short s_o1[G][AT * SO1]; // 16,320 B
    __shared__ __attribute__((aligned(16))) unsigned short s_o2[NC][OT * OT]; // 10,240 B

    const int bid  = blockIdx.x;
    const int img  = bid / 100;
    const int t100 = bid - img * 100;
    const int ty   = t100 / 10;
    const int tx   = t100 - ty * 10;
    const int y0   = ty * TS;
    const int x0   = tx * TS;
    const int tid  = threadIdx.x;

    const float* __restrict__ xi = x + (size_t)img * (512 * 512);
    const unsigned int* __restrict__ w1p = wp;
    const unsigned int* __restrict__ w2p = wp + W2_OFF;
    const unsigned int* __restrict__ w3p = wp + W3_OFF;

    const int t0 = 2 * y0 - 2;            // o1pad row base of tile
    const int s0 = 2 * x0 - 2;

    // ---- fill register cache: per thread up to 5 o1 positions' 16 x-taps ----
    unsigned int xr[5][8];
    int woff[5];
    bool pv[5];
    #pragma unroll
    for (int r = 0; r < 5; ++r) {
        const int p = tid + r * 256;
        pv[r] = false;
        woff[r] = 0;
        if (p < AT * AT) {
            const int a = p / AT;
            const int b = p - a * AT;
            const int t = t0 + a;          // o1pad row
            const int s = s0 + b;          // o1pad col
            if (t >= 0 && t <= 257 && s >= 0 && s <= 257) {
                pv[r] = true;
                woff[r] = a * SO1 + b;
                int m = t - 1; m = (m < 0) ? -m : m; m = (m > 255) ? 510 - m : m;
                int n = s - 1; n = (n < 0) ? -n : n; n = (n > 255) ? 510 - n : n;
                float rv[4][4];
                const int vb = 2 * n - 1;
                if (n >= 1 && n <= 254) {          // contiguous cols (bulk case)
                    #pragma unroll
                    for (int ki = 0; ki < 4; ++ki) {
                        int u = 2 * m - 1 + ki;
                        u = (u < 0) ? -u : u; u = (u > 511) ? 1022 - u : u;
                        const float* __restrict__ row = xi + u * 512 + vb;
                        rv[ki][0] = row[0]; rv[ki][1] = row[1];
                        rv[ki][2] = row[2]; rv[ki][3] = row[3];
                    }
                } else {                           // border cols: reflect per tap
                    int vc[4];
                    #pragma unroll
                    for (int kj = 0; kj < 4; ++kj) {
                        int v = vb + kj;
                        v = (v < 0) ? -v : v; v = (v > 511) ? 1022 - v : v;
                        vc[kj] = v;
                    }
                    #pragma unroll
                    for (int ki = 0; ki < 4; ++ki) {
                        int u = 2 * m - 1 + ki;
                        u = (u < 0) ? -u : u; u = (u > 511) ? 1022 - u : u;
                        const float* __restrict__ row = xi + u * 512;
                        rv[ki][0] = row[vc[0]]; rv[ki][1] = row[vc[1]];
                        rv[ki][2] = row[vc[2]]; rv[ki][3] = row[vc[3]];
                    }
                }
                #pragma unroll
                for (int ki = 0; ki < 4; ++ki) {
                    xr[r][2 * ki]     = pkrtz(rv[ki][0], rv[ki][1]);
                    xr[r][2 * ki + 1] = pkrtz(rv[ki][2], rv[ki][3]);
                }
            }
        }
    }

    float acc[NC];
    #pragma unroll
    for (int c = 0; c < NC; ++c) acc[c] = 0.f;

    const int il = tid >> 4, jl = tid & 15;
    const int oi = y0 - 1 + il, oj = x0 - 1 + jl;
    const bool bvalid = (oi >= 0 && oi < 128 && oj >= 0 && oj < 128);

    #pragma unroll
    for (int g = 0; g < NC / G; ++g) {
        if (g) __syncthreads();           // prev stage-B reads of s_o1 done

        // ---- stage A: registers -> s_o1[group g] (f16) ----
        #pragma unroll
        for (int r = 0; r < 5; ++r) {
            if (pv[r]) {
                #pragma unroll
                for (int cl = 0; cl < G; ++cl) {   // w1p uniform -> s_load
                    const int base = (g * G + cl) * 8;
                    float o = 0.f;
                    #pragma unroll
                    for (int kp = 0; kp < 8; ++kp)
                        o = dot2(xr[r][kp], w1p[base + kp], o);
                    s_o1[cl][woff[r]] = f2h(fmaxf(o, 0.f));
                }
            }
        }
        __syncthreads();

        // ---- stage B partial: s_o1 -> acc[20] ----
        if (bvalid) {
            const int a0 = 2 * il, b0 = 2 * jl;    // b0 even -> dword aligned
            #pragma unroll
            for (int cl = 0; cl < G; ++cl) {
                unsigned int o1r[8];
                #pragma unroll
                for (int ki = 0; ki < 4; ++ki) {
                    const unsigned int* row =
                        (const unsigned int*)&s_o1[cl][(a0 + ki) * SO1 + b0];
                    o1r[2 * ki]     = row[0];
                    o1r[2 * ki + 1] = row[1];
                }
                const int cing = g * G + cl;
                #pragma unroll
                for (int c = 0; c < NC; ++c) {     // w2p uniform -> s_load
                    const int base = (cing * NC + c) * 8;
                    #pragma unroll
                    for (int kp = 0; kp < 8; ++kp)
                        acc[c] = dot2(o1r[kp], w2p[base + kp], acc[c]);
                }
            }
        }
    }

    // ---- write s_o2 (f16; zeros at pad / out-of-image) ----
    #pragma unroll
    for (int c = 0; c < NC; ++c)
        s_o2[c][il * OT + jl] = bvalid ? f2h(fmaxf(acc[c], 0.f)) : (unsigned short)0;
    __syncthreads();

    // ---- stage C: 3x3 conv over s_o2 -> out ----
    if (tid < TS * TS) {
        const int oy = tid / TS;
        const int ox = tid - oy * TS;
        const int e  = ox & ~1;
        const int par = ox & 1;
        float accc = 0.f;
        for (int c = 0; c < NC; ++c) {
            #pragma unroll
            for (int di = 0; di < 3; ++di) {
                const unsigned int* row =
                    (const unsigned int*)&s_o2[c][(oy + di) * OT + e];
                const unsigned int d0 = row[0];
                const unsigned int d1 = row[1];
                const unsigned int m = __builtin_amdgcn_perm(d1, d0, 0x05040302u);
                const unsigned int u0 = par ? m : d0;
                const unsigned int wa = w3p[c * 9 + di * 3 + 0];
                const unsigned int wb = w3p[c * 9 + di * 3 + 1];
                const unsigned int wc = w3p[c * 9 + di * 3 + 2];
                accc = dot2(u0, wa, accc);
                accc = dot2(d1, par ? wc : wb, accc);
            }
        }
        const int gy = y0 + oy, gx = x0 + ox;
        if (gy < 128 && gx < 128)   // tiles cover 140>128 px: guard edge tiles
            out[(size_t)img * (128 * 128) + gy * 128 + gx] = fmaxf(accc, 0.f);
    }
}

extern "C" void kernel_launch(void* const* d_in, const int* in_sizes, int n_in,
                              void* d_out, int out_size, void* d_ws, size_t ws_size,
                              hipStream_t stream) {
    const float* x  = (const float*)d_in[0];
    const float* w1 = (const float*)d_in[1];
    const float* w2 = (const float*)d_in[2];
    const float* w3 = (const float*)d_in[3];
    unsigned int* wp = (unsigned int*)d_ws;
    float* out = (float*)d_out;
    pack_weights<<<dim3((WP_N + 255) / 256), dim3(256), 0, stream>>>(w1, w2, w3, wp);
    ds_fused<<<dim3(48 * 100), dim3(256), 0, stream>>>(x, wp, out);
}

// Round 7
// 177.717 us; speedup vs baseline: 9.2525x; 1.5042x over previous
//
#include <hip/hip_runtime.h>

// DownSampler fused: x[16,3,512,512] -> out[16,3,128,128] (C folded into N: 48 imgs)
//  S1: reflect-pad1 + 4x4/s2 conv (1->20) + relu   (VALU dot2, reg-cached taps)
//  S2: reflect-pad1 + 4x4/s2 conv (20->20) + relu  (MFMA 32x32x16 bf16)
//  S3: 3x3 zero-pad1 conv (20->1) + relu           (VALU dot2)
//
// Round 7: stage B moved to the matrix pipe. Per wave: 2 chunks x 32 positions,
// C[pos][cout] accumulated over K=320 (20 cin x 16 taps) in 40 mfmas. o1 staged
// as bf16 in LDS (stride 48: conflict-free); w2 pre-packed into MFMA B-layout
// fragments (bf16) in d_ws. Stage A writes ZEROS to invalid o1pad slots (mfma
// reads all of 34x34; 0xAA poison would poison borders). s_o2 stride 258 makes
// the C-layout epilogue scatter conflict-free.

#define NC 20
#define G  5      // stage-1 channel group
#define TS 14     // output tile
#define AT 34     // o1pad tile
#define SO1 48    // s_o1 row stride in shorts
#define SO2 258   // s_o2 channel stride in shorts (129 dwords: conflict-free)

// d_ws layout (u32):
//   [0,160)        w1p[ch][kp]        f16 pairs, ch<20, kp<8
//   [160,3360)     (unused, kept for layout stability)
//   [3360,3540)    w3p[c][di][which]  f16 pairs; 0=(w0,w1) 1=(w2,0) 2=(0,w2)
//   [3540,8660)    w2f[cin][lane][4]  bf16 MFMA B-frags: lane l holds
//                  B[k=(l>>5)*8+j][cout=l&31] = w2[cout][cin][k], j=0..7
#define W3_OFF  3360
#define W2F_OFF 3540
#define WP_N    8660

typedef _Float16 h2  __attribute__((ext_vector_type(2)));
typedef __fp16   hq2 __attribute__((ext_vector_type(2)));   // cvt_pkrtz ret type
typedef short    s16x8 __attribute__((ext_vector_type(8))); // 8 bf16 (4 VGPRs)
typedef float    f32x16 __attribute__((ext_vector_type(16)));

__device__ __forceinline__ float dot2(unsigned int a, unsigned int b, float c) {
    return __builtin_amdgcn_fdot2(__builtin_bit_cast(h2, a),
                                  __builtin_bit_cast(h2, b), c, false);
}
__device__ __forceinline__ unsigned int packh(float a, float b) {
    _Float16 ha = (_Float16)a, hb = (_Float16)b;
    return (unsigned int)__builtin_bit_cast(unsigned short, ha) |
           ((unsigned int)__builtin_bit_cast(unsigned short, hb) << 16);
}
__device__ __forceinline__ unsigned int pkrtz(float a, float b) {
    hq2 r = __builtin_amdgcn_cvt_pkrtz(a, b);
    return __builtin_bit_cast(unsigned int, r);
}
__device__ __forceinline__ unsigned short f2h(float a) {
    _Float16 h = (_Float16)a;
    return __builtin_bit_cast(unsigned short, h);
}
__device__ __forceinline__ unsigned short f2bf(float v) {
    unsigned int b = __float_as_uint(v);
    b += 0x7fffu + ((b >> 16) & 1u);   // RNE
    return (unsigned short)(b >> 16);
}
__device__ __forceinline__ unsigned int packbf(float a, float b) {
    return (unsigned int)f2bf(a) | ((unsigned int)f2bf(b) << 16);
}

__global__ __launch_bounds__(256) void pack_weights(
    const float* __restrict__ w1, const float* __restrict__ w2,
    const float* __restrict__ w3, unsigned int* __restrict__ wp)
{
    const int i = blockIdx.x * 256 + threadIdx.x;
    if (i >= WP_N) return;
    if (i < 160) {                          // w1p: f16 pairs
        const int ch = i >> 3, kp = i & 7;
        wp[i] = packh(w1[ch * 16 + 2 * kp], w1[ch * 16 + 2 * kp + 1]);
    } else if (i < W3_OFF) {
        wp[i] = 0;                          // unused gap
    } else if (i < W2F_OFF) {               // w3p: f16 pairs
        const int t = i - W3_OFF;
        const int c = t / 9;
        const int r = t - c * 9;
        const int di = r / 3, wh = r - di * 3;
        const float* row = w3 + c * 9 + di * 3;
        float a, b;
        if (wh == 0)      { a = row[0]; b = row[1]; }
        else if (wh == 1) { a = row[2]; b = 0.f;    }
        else              { a = 0.f;    b = row[2]; }
        wp[i] = packh(a, b);
    } else {                                // w2f: bf16 MFMA B-fragments
        const int t = i - W2F_OFF;          // [cin][lane][4 u32]
        const int cin  = t >> 8;            // 256 u32 per cin
        const int r    = t & 255;
        const int lane = r >> 2;
        const int jp   = r & 3;
        const int cout = lane & 31;
        const int k0   = (lane >> 5) * 8 + 2 * jp;
        float a = 0.f, b = 0.f;
        if (cout < NC) {
            a = w2[(cout * NC + cin) * 16 + k0];
            b = w2[(cout * NC + cin) * 16 + k0 + 1];
        }
        wp[i] = packbf(a, b);
    }
}

__global__ __launch_bounds__(256, 4) void ds_fused(
    const float* __restrict__ x,              // [48][512][512]
    const unsigned int* __restrict__ wp,      // packed weights (d_ws)
    float* __restrict__ out)                  // [48][128][128]
{
    __shared__ __attribute__((aligned(16))) unsigned short s_o1[G][AT * SO1]; // 16,320 B
    __shared__ __attribute__((aligned(16))) unsigned short s_o2[NC * SO2];    // 10,320 B

    const int bid  = blockIdx.x;
    const int img  = bid / 100;
    const int t100 = bid - img * 100;
    const int ty   = t100 / 10;
    const int tx   = t100 - ty * 10;
    const int y0   = ty * TS;
    const int x0   = tx * TS;
    const int tid  = threadIdx.x;
    const int lane = tid & 63;
    const int wv   = tid >> 6;               // wave 0..3; chunks 2wv, 2wv+1

    const float* __restrict__ xi = x + (size_t)img * (512 * 512);
    const unsigned int* __restrict__ w1p = wp;
    const unsigned int* __restrict__ w3p = wp + W3_OFF;
    const uint4* __restrict__ w2f = (const uint4*)(wp + W2F_OFF); // [cin*64+lane]

    const int t0 = 2 * y0 - 2;            // o1pad row base of tile
    const int s0 = 2 * x0 - 2;

    // ---- fill register cache: per thread up to 5 o1 positions' 16 x-taps ----
    unsigned int xr[5][8];
    int woff[5];
    bool pv[5];
    #pragma unroll
    for (int r = 0; r < 5; ++r) {
        const int p = tid + r * 256;
        pv[r] = false;
        woff[r] = -1;
        if (p < AT * AT) {
            const int a = p / AT;
            const int b = p - a * AT;
            woff[r] = a * SO1 + b;
            const int t = t0 + a;          // o1pad row
            const int s = s0 + b;          // o1pad col
            if (t >= 0 && t <= 257 && s >= 0 && s <= 257) {
                pv[r] = true;
                int m = t - 1; m = (m < 0) ? -m : m; m = (m > 255) ? 510 - m : m;
                int n = s - 1; n = (n < 0) ? -n : n; n = (n > 255) ? 510 - n : n;
                float rv[4][4];
                const int vb = 2 * n - 1;
                if (n >= 1 && n <= 254) {          // contiguous cols (bulk case)
                    #pragma unroll
                    for (int ki = 0; ki < 4; ++ki) {
                        int u = 2 * m - 1 + ki;
                        u = (u < 0) ? -u : u; u = (u > 511) ? 1022 - u : u;
                        const float* __restrict__ row = xi + u * 512 + vb;
                        rv[ki][0] = row[0]; rv[ki][1] = row[1];
                        rv[ki][2] = row[2]; rv[ki][3] = row[3];
                    }
                } else {                           // border cols: reflect per tap
                    int vc[4];
                    #pragma unroll
                    for (int kj = 0; kj < 4; ++kj) {
                        int v = vb + kj;
                        v = (v < 0) ? -v : v; v = (v > 511) ? 1022 - v : v;
                        vc[kj] = v;
                    }
                    #pragma unroll
                    for (int ki = 0; ki < 4; ++ki) {
                        int u = 2 * m - 1 + ki;
                        u = (u < 0) ? -u : u; u = (u > 511) ? 1022 - u : u;
                        const float* __restrict__ row = xi + u * 512;
                        rv[ki][0] = row[vc[0]]; rv[ki][1] = row[vc[1]];
                        rv[ki][2] = row[vc[2]]; rv[ki][3] = row[vc[3]];
                    }
                }
                #pragma unroll
                for (int ki = 0; ki < 4; ++ki) {
                    xr[r][2 * ki]     = pkrtz(rv[ki][0], rv[ki][1]);
                    xr[r][2 * ki + 1] = pkrtz(rv[ki][2], rv[ki][3]);
                }
            }
        }
    }

    // ---- MFMA A-frag LDS offsets (shorts), constant across groups ----
    const int kh  = lane >> 5;                         // K-half
    const int l31 = lane & 31;
    const int il0 = 4 * wv + (l31 >> 4);               // chunk 2wv: il
    const int b0  = 2 * (lane & 15);
    const int offA0 = (2 * il0 + 2 * kh) * SO1 + b0;   // chunk 2wv, row r0
    const int offA1 = offA0 + 4 * SO1;                 // chunk 2wv+1 (il+2)

    f32x16 acc0 = {};
    f32x16 acc1 = {};

    #pragma unroll
    for (int g = 0; g < NC / G; ++g) {
        if (g) __syncthreads();           // prev stage-B reads of s_o1 done

        // ---- stage A: registers -> s_o1[group g] (bf16); zeros at invalid ----
        #pragma unroll
        for (int r = 0; r < 5; ++r) {
            if (woff[r] >= 0) {
                if (pv[r]) {
                    #pragma unroll
                    for (int cl = 0; cl < G; ++cl) {   // w1p uniform -> s_load
                        const int base = (g * G + cl) * 8;
                        float o = 0.f;
                        #pragma unroll
                        for (int kp = 0; kp < 8; ++kp)
                            o = dot2(xr[r][kp], w1p[base + kp], o);
                        s_o1[cl][woff[r]] = f2bf(fmaxf(o, 0.f));
                    }
                } else {
                    #pragma unroll
                    for (int cl = 0; cl < G; ++cl)
                        s_o1[cl][woff[r]] = 0;
                }
            }
        }
        __syncthreads();

        // ---- stage B: MFMA over this group's 5 cin (K-steps of 16) ----
        #pragma unroll
        for (int cl = 0; cl < G; ++cl) {
            const int cin = g * G + cl;
            const uint4 bw = w2f[cin * 64 + lane];     // B-frag (L1-resident)
            const s16x8 bfrag = __builtin_bit_cast(s16x8, bw);

            const unsigned short* p0 = &s_o1[cl][offA0];
            uint4 aw0;
            aw0.x = *(const unsigned int*)(p0);
            aw0.y = *(const unsigned int*)(p0 + 2);
            aw0.z = *(const unsigned int*)(p0 + SO1);
            aw0.w = *(const unsigned int*)(p0 + SO1 + 2);
            acc0 = __builtin_amdgcn_mfma_f32_32x32x16_bf16(
                       __builtin_bit_cast(s16x8, aw0), bfrag, acc0, 0, 0, 0);

            const unsigned short* p1 = &s_o1[cl][offA1];
            uint4 aw1;
            aw1.x = *(const unsigned int*)(p1);
            aw1.y = *(const unsigned int*)(p1 + 2);
            aw1.z = *(const unsigned int*)(p1 + SO1);
            aw1.w = *(const unsigned int*)(p1 + SO1 + 2);
            acc1 = __builtin_amdgcn_mfma_f32_32x32x16_bf16(
                       __builtin_bit_cast(s16x8, aw1), bfrag, acc1, 0, 0, 0);
        }
    }

    // ---- epilogue: C-layout acc -> s_o2 (f16; zeros at invalid positions) ----
    // C/D: cout = lane&31, m = (reg&3) + 8*(reg>>2) + 4*kh   [verified layout]
    const int cout = l31;
    #pragma unroll
    for (int ch = 0; ch < 2; ++ch) {
        const int chunk = 2 * wv + ch;
        #pragma unroll
        for (int reg = 0; reg < 16; ++reg) {
            const int m   = (reg & 3) + 8 * (reg >> 2) + 4 * kh;
            const int pos = chunk * 32 + m;
            const int il  = pos >> 4, jl = pos & 15;
            const int oi  = y0 - 1 + il, oj = x0 - 1 + jl;
            const bool val = (oi >= 0 && oi < 128 && oj >= 0 && oj < 128);
            const float v = (ch == 0) ? acc0[reg] : acc1[reg];
            if (cout < NC)
                s_o2[cout * SO2 + il * 16 + jl] =
                    val ? f2h(fmaxf(v, 0.f)) : (unsigned short)0;
        }
    }
    __syncthreads();

    // ---- stage C: 3x3 conv over s_o2 -> out ----
    if (tid < TS * TS) {
        const int oy = tid / TS;
        const int ox = tid - oy * TS;
        const int e  = ox & ~1;
        const int par = ox & 1;
        float accc = 0.f;
        for (int c = 0; c < NC; ++c) {
            #pragma unroll
            for (int di = 0; di < 3; ++di) {
                const unsigned int* row =
                    (const unsigned int*)&s_o2[c * SO2 + (oy + di) * 16 + e];
                const unsigned int d0 = row[0];
                const unsigned int d1 = row[1];
                const unsigned int mm = __builtin_amdgcn_perm(d1, d0, 0x05040302u);
                const unsigned int u0 = par ? mm : d0;
                const unsigned int wa = w3p[c * 9 + di * 3 + 0];
                const unsigned int wb = w3p[c * 9 + di * 3 + 1];
                const unsigned int wc = w3p[c * 9 + di * 3 + 2];
                accc = dot2(u0, wa, accc);
                accc = dot2(d1, par ? wc : wb, accc);
            }
        }
        const int gy = y0 + oy, gx = x0 + ox;
        if (gy < 128 && gx < 128)   // tiles cover 140>128 px: guard edge tiles
            out[(size_t)img * (128 * 128) + gy * 128 + gx] = fmaxf(accc, 0.f);
    }
}

extern "C" void kernel_launch(void* const* d_in, const int* in_sizes, int n_in,
                              void* d_out, int out_size, void* d_ws, size_t ws_size,
                              hipStream_t stream) {
    const float* x  = (const float*)d_in[0];
    const float* w1 = (const float*)d_in[1];
    const float* w2 = (const float*)d_in[2];
    const float* w3 = (const float*)d_in[3];
    unsigned int* wp = (unsigned int*)d_ws;
    float* out = (float*)d_out;
    pack_weights<<<dim3((WP_N + 255) / 256), dim3(256), 0, stream>>>(w1, w2, w3, wp);
    ds_fused<<<dim3(48 * 100), dim3(256), 0, stream>>>(x, wp, out);
}